// Round 3
// baseline (219.443 us; speedup 1.0000x reference)
//
#include <hip/hip_runtime.h>
#include <hip/hip_bf16.h>
#include <math.h>

typedef __attribute__((ext_vector_type(8))) short bf16x8;
typedef __attribute__((ext_vector_type(4))) float f32x4;

// ---------------- qkv projection: q/k/v = X @ W + b (f32 out to ws) ----------
__global__ void qkv_proj_kernel(const float* __restrict__ query,
                                const float* __restrict__ key,
                                const float* __restrict__ value,
                                const float* __restrict__ Wq, const float* __restrict__ bq,
                                const float* __restrict__ Wk, const float* __restrict__ bk,
                                const float* __restrict__ Wv, const float* __restrict__ bv,
                                float* __restrict__ qf, float* __restrict__ kf,
                                float* __restrict__ vf)
{
    const int mat = blockIdx.x >> 8;   // 0:q 1:k 2:v
    const int rb  = blockIdx.x & 255;  // 16-row block of 4096 rows
    const float* X; const float* W; const float* bias; float* dst;
    if (mat == 0)      { X = query; W = Wq; bias = bq; dst = qf; }
    else if (mat == 1) { X = key;   W = Wk; bias = bk; dst = kf; }
    else               { X = value; W = Wv; bias = bv; dst = vf; }

    __shared__ float sX[16][128];
    const int tid = threadIdx.x;
    const float* src = X + (size_t)rb * 16 * 128;
    #pragma unroll
    for (int i = 0; i < 8; ++i) {
        int idx = tid + i * 256;
        sX[idx >> 7][idx & 127] = src[idx];
    }
    __syncthreads();

    const int col = tid & 127;
    const int rg  = tid >> 7;
    float acc[8] = {0.f,0.f,0.f,0.f,0.f,0.f,0.f,0.f};
    for (int e = 0; e < 128; ++e) {
        float w = W[e * 128 + col];
        #pragma unroll
        for (int r = 0; r < 8; ++r) acc[r] += sX[rg * 8 + r][e] * w;
    }
    float bb = bias[col];
    #pragma unroll
    for (int r = 0; r < 8; ++r)
        dst[(size_t)(rb * 16 + rg * 8 + r) * 128 + col] = acc[r] + bb;
}

// ---------------- fused main kernel: one workgroup per (b, n) ----------------
// score_pe[m,h] = relpe[m,:] . Wtilde[:,h],  Wtilde = Wpe_hblock @ (q_h/SCALE)
// out_pe[h,:]   = (sum_m P[m,h] relpe[m,:]) @ Wpe_hblock
// qk scores + mask hoisted to prologue (sS); GEMM1 C-init folds them in.
// Register high-water kept < 128 so __launch_bounds__(256,4) doesn't spill.
__global__ __launch_bounds__(256, 4) void mha_main_kernel(
    const float* __restrict__ relpe,
    const float* __restrict__ mask,
    const float* __restrict__ qf,
    const float* __restrict__ kf,
    const float* __restrict__ vf,
    const float* __restrict__ Wpe, const float* __restrict__ bpe,
    const float* __restrict__ Wo,  const float* __restrict__ bo,
    float* __restrict__ out)
{
    __shared__ __hip_bfloat16 sA[64][136];   // rel_pe tile bf16
    __shared__ __hip_bfloat16 sWt[16][136];  // sWt[h][e] = Wtilde[e][h] bf16
    __shared__ __hip_bfloat16 sPb[16][72];   // P bf16, [h][m]
    __shared__ float sS[8][256];             // scores qk+mask (prologue), +cb+pe per tile; epilogue: pr
    __shared__ float sPf[8][64];             // P f32
    __shared__ float sQs[128];               // q / SCALE
    __shared__ float sCb[8];
    __shared__ float sM[8], sL[8];
    __shared__ float sRf[16];
    __shared__ float sRed[128];
    __shared__ float sOut[128];

    const int tid  = threadIdx.x;
    const int lane = tid & 63;
    const int wv   = tid >> 6;
    // XCD-aware bijective swizzle (4096 % 8 == 0): each XCD gets 512 contiguous wgs
    const int bid  = ((blockIdx.x & 7) << 9) | (blockIdx.x >> 3);
    const int b    = bid >> 8;
    const int n    = bid & 255;
    const size_t bn = (size_t)(b * 256 + n);

    // ---- prefetch tile 0 into registers (overlaps whole prologue)
    float4 pf[8];
    {
        const float4* s4 = (const float4*)(relpe + (bn * 256) * 128);
        #pragma unroll
        for (int i = 0; i < 8; ++i) pf[i] = s4[tid + i * 256];
    }

    if (tid < 128) sQs[tid] = qf[bn * 128 + tid] * 0.25f;
    if (tid < 8)  { sM[tid] = -INFINITY; sL[tid] = 0.f; }
    if (tid < 16) sRf[tid] = 1.f;
    if (tid < 72) {
        #pragma unroll
        for (int r = 8; r < 16; ++r) sPb[r][tid] = __float2bfloat16(0.f);
    }
    if (tid < 128) {
        #pragma unroll
        for (int r = 8; r < 16; ++r) sWt[r][tid] = __float2bfloat16(0.f);
    }
    __syncthreads();   // sQs ready

    // ---- Wtilde[e][h] = sum_d Wpe[e][h*16+d] * qs[h*16+d]  (stored transposed)
    #pragma unroll
    for (int o = tid; o < 1024; o += 256) {
        int h = o >> 7, e = o & 127;
        const float4* wr = (const float4*)(Wpe + (size_t)e * 128 + h * 16);
        float4 w0 = wr[0], w1 = wr[1], w2 = wr[2], w3 = wr[3];
        const float* qh = &sQs[h * 16];
        float acc = w0.x*qh[0]+w0.y*qh[1]+w0.z*qh[2]+w0.w*qh[3]
                  + w1.x*qh[4]+w1.y*qh[5]+w1.z*qh[6]+w1.w*qh[7]
                  + w2.x*qh[8]+w2.y*qh[9]+w2.z*qh[10]+w2.w*qh[11]
                  + w3.x*qh[12]+w3.y*qh[13]+w3.z*qh[14]+w3.w*qh[15];
        sWt[h][e] = __float2bfloat16(acc);
    }
    if (tid < 8) {
        float acc = 0.f;
        #pragma unroll
        for (int d = 0; d < 16; ++d) acc += bpe[tid * 16 + d] * sQs[tid * 16 + d];
        sCb[tid] = acc;
    }

    const int hsc = tid >> 5;      // head for score work
    const int ml  = tid & 31;      // m-lane
    // ---- prologue qk scores: sS[h][m] = q_h . k_h[m] / SCALE + mask  (once!)
    #pragma unroll
    for (int i = 0; i < 8; ++i) {
        int m = i * 32 + ml;
        const float4* k4 = (const float4*)(kf + ((size_t)(b * 256) + m) * 128 + hsc * 16);
        float4 ka = k4[0], kb = k4[1], kc = k4[2], kd = k4[3];
        const float* qh = &sQs[hsc * 16];
        float s = ka.x*qh[0]+ka.y*qh[1]+ka.z*qh[2]+ka.w*qh[3]
                + kb.x*qh[4]+kb.y*qh[5]+kb.z*qh[6]+kb.w*qh[7]
                + kc.x*qh[8]+kc.y*qh[9]+kc.z*qh[10]+kc.w*qh[11]
                + kd.x*qh[12]+kd.y*qh[13]+kd.z*qh[14]+kd.w*qh[15];
        sS[hsc][m] = s + mask[bn * 256 + m];
    }

    // ---- write tile 0 to sA (bf16)
    #pragma unroll
    for (int i = 0; i < 8; ++i) {
        int idx4 = tid + i * 256;
        int lr = idx4 >> 5, c4 = (idx4 & 31) * 4;
        __hip_bfloat162* dp = (__hip_bfloat162*)&sA[lr][c4];
        dp[0] = __float22bfloat162_rn(make_float2(pf[i].x, pf[i].y));
        dp[1] = __float22bfloat162_rn(make_float2(pf[i].z, pf[i].w));
    }
    __syncthreads();

    float out_acc = 0.f;
    f32x4 pr0 = {}, pr1 = {};
    const int e     = tid & 127;
    const int halfp = tid >> 7;
    const int hh    = e >> 4;
    const int arow  = lane & 15;
    const int koff  = lane >> 4;

    for (int t = 0; t < 4; ++t) {
        // issue next tile's global loads (in flight across all compute)
        if (t < 3) {
            const float4* s4 = (const float4*)(relpe + (bn * 256 + (t + 1) * 64) * 128);
            #pragma unroll
            for (int i = 0; i < 8; ++i) pf[i] = s4[tid + i * 256];
        }

        // ---- GEMM1: total score = (qk+mask) + cb + relpe_tile @ Wtilde, in place
        f32x4 cs;
        #pragma unroll
        for (int r = 0; r < 4; ++r) {
            int row = wv * 16 + koff * 4 + r;
            cs[r] = (arow < 8) ? (sS[arow][t * 64 + row] + sCb[arow]) : 0.f;
        }
        #pragma unroll
        for (int kt = 0; kt < 4; ++kt) {
            bf16x8 af  = *(const bf16x8*)&sA[wv * 16 + arow][kt * 32 + koff * 8];
            bf16x8 bfr = *(const bf16x8*)&sWt[arow][kt * 32 + koff * 8];
            cs = __builtin_amdgcn_mfma_f32_16x16x32_bf16(af, bfr, cs, 0, 0, 0);
        }
        if (arow < 8) {
            #pragma unroll
            for (int r = 0; r < 4; ++r)
                sS[arow][t * 64 + wv * 16 + koff * 4 + r] = cs[r];
        }
        __syncthreads();

        // ---- softmax (LDS-only): online update
        {
            float sc0 = sS[hsc][t * 64 + ml];
            float sc1 = sS[hsc][t * 64 + ml + 32];
            float tm = fmaxf(sc0, sc1);
            #pragma unroll
            for (int m2 = 16; m2 >= 1; m2 >>= 1) tm = fmaxf(tm, __shfl_xor(tm, m2, 32));
            float mold = sM[hsc];
            float mnew = fmaxf(mold, tm);
            float p0 = __expf(sc0 - mnew), p1 = __expf(sc1 - mnew);
            float ts = p0 + p1;
            #pragma unroll
            for (int m2 = 16; m2 >= 1; m2 >>= 1) ts += __shfl_xor(ts, m2, 32);
            if (ml == 0) {
                float rf = __expf(mold - mnew);
                sRf[hsc] = rf;
                sM[hsc]  = mnew;
                sL[hsc]  = sL[hsc] * rf + ts;
            }
            sPf[hsc][ml]      = p0;
            sPf[hsc][ml + 32] = p1;
            sPb[hsc][ml]      = __float2bfloat16(p0);
            sPb[hsc][ml + 32] = __float2bfloat16(p1);
        }
        __syncthreads();

        // ---- GEMM2: pr += P^T @ relpe_tile (MFMA); PV via VALU (v f32 from L2)
        {
            #pragma unroll
            for (int r = 0; r < 4; ++r) {
                float rf = sRf[koff * 4 + r];
                pr0[r] *= rf; pr1[r] *= rf;
            }
            #pragma unroll
            for (int kt = 0; kt < 2; ++kt) {
                bf16x8 ap = *(const bf16x8*)&sPb[arow][kt * 32 + koff * 8];
                bf16x8 b0, b1;
                #pragma unroll
                for (int j = 0; j < 8; ++j) {
                    int row = kt * 32 + koff * 8 + j;
                    b0[j] = *(const short*)&sA[row][wv * 32 + arow];
                    b1[j] = *(const short*)&sA[row][wv * 32 + 16 + arow];
                }
                pr0 = __builtin_amdgcn_mfma_f32_16x16x32_bf16(ap, b0, pr0, 0, 0, 0);
                pr1 = __builtin_amdgcn_mfma_f32_16x16x32_bf16(ap, b1, pr1, 0, 0, 0);
            }
            out_acc *= sRf[hh];
            const float* vp = vf + ((size_t)(b * 256) + t * 64 + halfp * 32) * 128 + e;
            const float* pp = &sPf[hh][halfp * 32];
            #pragma unroll 8
            for (int mm = 0; mm < 32; ++mm)
                out_acc += pp[mm] * vp[(size_t)mm * 128];
        }
        __syncthreads();   // all sA reads done

        if (t < 3) {
            #pragma unroll
            for (int i = 0; i < 8; ++i) {
                int idx4 = tid + i * 256;
                int lr = idx4 >> 5, c4 = (idx4 & 31) * 4;
                __hip_bfloat162* dp = (__hip_bfloat162*)&sA[lr][c4];
                dp[0] = __float22bfloat162_rn(make_float2(pf[i].x, pf[i].y));
                dp[1] = __float22bfloat162_rn(make_float2(pf[i].z, pf[i].w));
            }
            __syncthreads();
        }
    }

    // ---- epilogue (sS is dead as scores; reuse rows 0-7 cols 0-127 for pr)
    if (halfp) sRed[e] = out_acc;
    #pragma unroll
    for (int r = 0; r < 4; ++r) {
        int row = koff * 4 + r;
        if (row < 8) {
            sS[row][wv * 32 + arow]      = pr0[r];
            sS[row][wv * 32 + 16 + arow] = pr1[r];
        }
    }
    __syncthreads();
    float outv = out_acc + (halfp ? 0.f : sRed[e]);   // valid for halfp==0
    __syncthreads();

    // out_pe partial: halves split the e-sum
    float ype = 0.f;
    {
        const float* wp  = Wpe + (size_t)(halfp * 64) * 128 + e;
        const float* prh = &sS[hh][halfp * 64];
        #pragma unroll 8
        for (int ee = 0; ee < 64; ++ee) ype += prh[ee] * wp[(size_t)ee * 128];
    }
    if (halfp) sRed[e] = ype;
    __syncthreads();
    if (!halfp) sOut[e] = (outv + ype + sRed[e]) / sL[hh] + bpe[e];
    __syncthreads();

    // ---- y = out @ Wo + bo
    float y = 0.f;
    {
        const float* wo = Wo + (size_t)(halfp * 64) * 128 + e;
        #pragma unroll 8
        for (int ee = 0; ee < 64; ++ee) y += sOut[halfp * 64 + ee] * wo[(size_t)ee * 128];
    }
    if (halfp) sRed[e] = y;
    __syncthreads();
    if (!halfp) out[bn * 128 + e] = y + sRed[e] + bo[e];
}

extern "C" void kernel_launch(void* const* d_in, const int* in_sizes, int n_in,
                              void* d_out, int out_size, void* d_ws, size_t ws_size,
                              hipStream_t stream)
{
    const float* query = (const float*)d_in[0];
    const float* key   = (const float*)d_in[1];
    const float* value = (const float*)d_in[2];
    const float* relpe = (const float*)d_in[3];
    const float* mask  = (const float*)d_in[4];
    const float* Wq  = (const float*)d_in[5];
    const float* bq  = (const float*)d_in[6];
    const float* Wk  = (const float*)d_in[7];
    const float* bk  = (const float*)d_in[8];
    const float* Wv  = (const float*)d_in[9];
    const float* bv  = (const float*)d_in[10];
    const float* Wpe = (const float*)d_in[11];
    const float* bpe = (const float*)d_in[12];
    const float* Wo  = (const float*)d_in[13];
    const float* bo  = (const float*)d_in[14];
    float* out = (float*)d_out;

    float* qf = (float*)d_ws;                  // 2 MB
    float* kf = qf + 16 * 256 * 128;           // 2 MB
    float* vf = kf + 16 * 256 * 128;           // 2 MB

    qkv_proj_kernel<<<dim3(768), dim3(256), 0, stream>>>(
        query, key, value, Wq, bq, Wk, bk, Wv, bv, qf, kf, vf);
    mha_main_kernel<<<dim3(4096), dim3(256), 0, stream>>>(
        relpe, mask, qf, kf, vf, Wpe, bpe, Wo, bo, out);
}